// Round 3
// baseline (29262.354 us; speedup 1.0000x reference)
//
#include <hip/hip_runtime.h>
#include <hip/hip_bf16.h>

#define TT 512
#define BB 64
#define DD 1024
#define HH 1024
#define NG4 4096
#define NWG 128

typedef short bf16x8 __attribute__((ext_vector_type(8)));
typedef float f32x4 __attribute__((ext_vector_type(4)));
typedef __hip_bfloat16 bf16;

static __device__ __forceinline__ unsigned short bfbits(float f) {
  bf16 h = __float2bfloat16(f);
  return *reinterpret_cast<unsigned short*>(&h);
}
static __device__ __forceinline__ float bf2f(unsigned short u) {
  bf16 h = *reinterpret_cast<bf16*>(&u);
  return __bfloat162float(h);
}

// ---------------- cast: fp32 -> bf16 hi + bf16 lo(residual) ----------------
__global__ __launch_bounds__(256) void cast_hilo(const float* __restrict__ in,
                                                 bf16* __restrict__ hi,
                                                 bf16* __restrict__ lo,
                                                 int n4) {
  int i = blockIdx.x * 256 + threadIdx.x;
  if (i >= n4) return;
  float4 v = reinterpret_cast<const float4*>(in)[i];
  float f[4] = {v.x, v.y, v.z, v.w};
  int base = i * 4;
#pragma unroll
  for (int j = 0; j < 4; ++j) {
    bf16 h = __float2bfloat16(f[j]);
    hi[base + j] = h;
    lo[base + j] = __float2bfloat16(f[j] - __bfloat162float(h));
  }
}

// ---------------- pack w_hh into per-WG fragment-major hi/lo ----------------
// dst group idx within wg: (kc*2+n)*64 + lane ; 8 elems per group.
// element (lane l, e): packed col p = n*16 + (l&15) -> gate q=p>>3, unit u=p&7
//                      k = kc*32 + (l>>4)*8 + e
// orig row = q*1024 + wg*8 + u  (w_hh [4096][1024] row-major)
__global__ __launch_bounds__(256) void pack_whh_frag(const float* __restrict__ w,
                                                     bf16* __restrict__ ph,
                                                     bf16* __restrict__ pl) {
  int gid = blockIdx.x * 256 + threadIdx.x;   // 128*4096 groups
  int wg  = gid >> 12;
  int rem = gid & 4095;
  int kc = rem >> 7, n = (rem >> 6) & 1, l = rem & 63;
  int p = n * 16 + (l & 15);
  int q = p >> 3, u = p & 7;
  int k = kc * 32 + (l >> 4) * 8;
  size_t src = (size_t)(q * 1024 + wg * 8 + u) * HH + k;
  float4 v0 = *reinterpret_cast<const float4*>(w + src);
  float4 v1 = *reinterpret_cast<const float4*>(w + src + 4);
  float f[8] = {v0.x, v0.y, v0.z, v0.w, v1.x, v1.y, v1.z, v1.w};
  short ho[8], lo[8];
#pragma unroll
  for (int j = 0; j < 8; ++j) {
    unsigned short hb = bfbits(f[j]);
    ho[j] = (short)hb;
    lo[j] = (short)bfbits(f[j] - bf2f(hb));
  }
  *reinterpret_cast<bf16x8*>(ph + (size_t)gid * 8) = *reinterpret_cast<bf16x8*>(ho);
  *reinterpret_cast<bf16x8*>(pl + (size_t)gid * 8) = *reinterpret_cast<bf16x8*>(lo);
}

// ---------------- 3-term split-bf16 MFMA GEMM, transposed epilogue ----------
// C written as xgT [t][4096][64]: dst = t*262144 + col*64 + b
#define BM 128
#define BN 128
#define BKK 64

__global__ __launch_bounds__(256) void gemm3(
    const bf16* __restrict__ Ah, const bf16* __restrict__ Al,
    const bf16* __restrict__ Bh, const bf16* __restrict__ Bl,
    const float* __restrict__ bias1, const float* __restrict__ bias2,
    float* __restrict__ C, int M, int N, int K)
{
  __shared__ bf16 sAh[BM][BKK], sAl[BM][BKK], sBh[BN][BKK], sBl[BN][BKK];
  const int tid  = threadIdx.x;
  const int lane = tid & 63;
  const int wv   = tid >> 6;
  const int wr   = wv >> 1, wc = wv & 1;
  const int nbx  = N / BN;
  const int bx   = blockIdx.x % nbx, by = blockIdx.x / nbx;
  const int l15  = lane & 15, l4 = lane >> 4;

  f32x4 acc[4][4] = {};

  for (int k0 = 0; k0 < K; k0 += BKK) {
    __syncthreads();
#pragma unroll
    for (int i = 0; i < 4; ++i) {
      int f  = i * 256 + tid;
      int r  = f >> 3;
      int kk = (f & 7) << 3;
      size_t ga = (size_t)(by * BM + r) * K + k0 + kk;
      size_t gb = (size_t)(bx * BN + r) * K + k0 + kk;
      *reinterpret_cast<bf16x8*>(&sAh[r][kk]) = *reinterpret_cast<const bf16x8*>(Ah + ga);
      *reinterpret_cast<bf16x8*>(&sAl[r][kk]) = *reinterpret_cast<const bf16x8*>(Al + ga);
      *reinterpret_cast<bf16x8*>(&sBh[r][kk]) = *reinterpret_cast<const bf16x8*>(Bh + gb);
      *reinterpret_cast<bf16x8*>(&sBl[r][kk]) = *reinterpret_cast<const bf16x8*>(Bl + gb);
    }
    __syncthreads();
#pragma unroll
    for (int kk = 0; kk < BKK; kk += 32) {
      const int kf = kk + (l4 << 3);
      bf16x8 a_h[4], a_l[4], b_h[4], b_l[4];
#pragma unroll
      for (int m = 0; m < 4; ++m) {
        a_h[m] = *reinterpret_cast<const bf16x8*>(&sAh[wr * 64 + m * 16 + l15][kf]);
        a_l[m] = *reinterpret_cast<const bf16x8*>(&sAl[wr * 64 + m * 16 + l15][kf]);
      }
#pragma unroll
      for (int n = 0; n < 4; ++n) {
        b_h[n] = *reinterpret_cast<const bf16x8*>(&sBh[wc * 64 + n * 16 + l15][kf]);
        b_l[n] = *reinterpret_cast<const bf16x8*>(&sBl[wc * 64 + n * 16 + l15][kf]);
      }
#pragma unroll
      for (int m = 0; m < 4; ++m)
#pragma unroll
        for (int n = 0; n < 4; ++n) {
          acc[m][n] = __builtin_amdgcn_mfma_f32_16x16x32_bf16(a_h[m], b_h[n], acc[m][n], 0, 0, 0);
          acc[m][n] = __builtin_amdgcn_mfma_f32_16x16x32_bf16(a_l[m], b_h[n], acc[m][n], 0, 0, 0);
          acc[m][n] = __builtin_amdgcn_mfma_f32_16x16x32_bf16(a_h[m], b_l[n], acc[m][n], 0, 0, 0);
        }
    }
  }
#pragma unroll
  for (int n = 0; n < 4; ++n) {
    int col = bx * BN + wc * 64 + n * 16 + l15;
    float bv = bias1[col] + bias2[col];
#pragma unroll
    for (int m = 0; m < 4; ++m) {
      int row0 = by * BM + wr * 64 + m * 16 + l4 * 4;
      int t = row0 >> 6, b0 = row0 & 63;
      float4 v;
      v.x = acc[m][n][0] + bv;
      v.y = acc[m][n][1] + bv;
      v.z = acc[m][n][2] + bv;
      v.w = acc[m][n][3] + bv;
      *reinterpret_cast<float4*>(C + (size_t)t * (NG4 * 64) + (size_t)col * 64 + b0) = v;
    }
  }
}

// ---------------- persistent chunk scan: CT timesteps, spin barrier --------
// 128 WGs x 256 thr. WG wg owns units j0=wg*8 (32 packed cols). LDS-resident w.
// Wave wv covers kc in [wv*8, wv*8+8), all 64 batches, both n-tiles.
// h carried in fragment-major ping-pong: hf[(parity)][ ((m*32+kc)*64+lane)*8 + e ]
__global__ __launch_bounds__(256, 1) void lstm_scan(
    const bf16* __restrict__ wpkh, const bf16* __restrict__ wpkl, // [128][32768]
    const float* __restrict__ xgT,   // [CT][4096][64], biases included
    bf16* __restrict__ hfh, bf16* __restrict__ hfl,  // [2][65536]
    float* __restrict__ cst,         // [64][1024]
    int* __restrict__ flags,         // [CT], zeroed
    int CT,
    bf16* __restrict__ svh, bf16* __restrict__ svl,  // [CT*64][1024] or null
    float* __restrict__ outp)        // [CT*64][1024] or null
{
  __shared__ bf16  sW[65536];        // hi at [0,32768), lo at [32768,65536)
  __shared__ float gredA[64][33];
  __shared__ float gredB[64][33];

  const int tid  = threadIdx.x;
  const int lane = tid & 63;
  const int wv   = tid >> 6;
  const int wg   = blockIdx.x;
  const int l15  = lane & 15, l4 = lane >> 4;
  const int j0   = wg * 8;

  // load w into LDS once
  {
    const bf16x8* srcH = reinterpret_cast<const bf16x8*>(wpkh + (size_t)wg * 32768);
    const bf16x8* srcL = reinterpret_cast<const bf16x8*>(wpkl + (size_t)wg * 32768);
    bf16x8* dstH = reinterpret_cast<bf16x8*>(sW);
    bf16x8* dstL = reinterpret_cast<bf16x8*>(sW + 32768);
    for (int i = tid; i < 4096; i += 256) { dstH[i] = srcH[i]; dstL[i] = srcL[i]; }
  }
  const int pb = tid & 63;        // pointwise: batch
  const int u0 = (tid >> 6) * 2;  // pointwise: unit pair
  float cR0 = cst[(size_t)pb * HH + j0 + u0];
  float cR1 = cst[(size_t)pb * HH + j0 + u0 + 1];
  __syncthreads();

  for (int s = 0; s < CT; ++s) {
    const bf16* hh = hfh + (size_t)(s & 1) * 65536;
    const bf16* hl = hfl + (size_t)(s & 1) * 65536;

    // prefetch xg for this thread's pointwise (hides HBM latency under MFMA)
    const float* xgs = xgT + (size_t)s * (NG4 * 64);
    float xq[2][4];
#pragma unroll
    for (int d = 0; d < 2; ++d) {
      int u = j0 + u0 + d;
#pragma unroll
      for (int q = 0; q < 4; ++q)
        xq[d][q] = xgs[(size_t)(q * 1024 + u) * 64 + pb];
    }

    f32x4 acc[4][2] = {};
#pragma unroll
    for (int kk = 0; kk < 8; ++kk) {
      const int kc = wv * 8 + kk;
      bf16x8 bh[2], bl[2];
#pragma unroll
      for (int n = 0; n < 2; ++n) {
        const int wi = ((kc * 2 + n) * 64 + lane) * 8;
        bh[n] = *reinterpret_cast<const bf16x8*>(sW + wi);
        bl[n] = *reinterpret_cast<const bf16x8*>(sW + 32768 + wi);
      }
#pragma unroll
      for (int m = 0; m < 4; ++m) {
        const size_t ai = ((size_t)(m * 32 + kc) * 64 + lane) * 8;
        bf16x8 ah = *reinterpret_cast<const bf16x8*>(hh + ai);
        bf16x8 al = *reinterpret_cast<const bf16x8*>(hl + ai);
#pragma unroll
        for (int n = 0; n < 2; ++n) {
          acc[m][n] = __builtin_amdgcn_mfma_f32_16x16x32_bf16(ah, bh[n], acc[m][n], 0, 0, 0);
          acc[m][n] = __builtin_amdgcn_mfma_f32_16x16x32_bf16(al, bh[n], acc[m][n], 0, 0, 0);
          acc[m][n] = __builtin_amdgcn_mfma_f32_16x16x32_bf16(ah, bl[n], acc[m][n], 0, 0, 0);
        }
      }
    }

    // cross-wave K reduction (tree via LDS)
#define STORE_ACC(G)                                            \
    {_Pragma("unroll") for (int m = 0; m < 4; ++m)              \
     _Pragma("unroll") for (int n = 0; n < 2; ++n)              \
     _Pragma("unroll") for (int r = 0; r < 4; ++r)              \
       G[m * 16 + l4 * 4 + r][n * 16 + l15] = acc[m][n][r];}
#define ADD_ACC(G)                                              \
    {_Pragma("unroll") for (int m = 0; m < 4; ++m)              \
     _Pragma("unroll") for (int n = 0; n < 2; ++n)              \
     _Pragma("unroll") for (int r = 0; r < 4; ++r)              \
       acc[m][n][r] += G[m * 16 + l4 * 4 + r][n * 16 + l15];}

    if (wv == 1)      STORE_ACC(gredA)
    else if (wv == 3) STORE_ACC(gredB)
    __syncthreads();
    if (wv == 0)      ADD_ACC(gredA)
    else if (wv == 2) ADD_ACC(gredB)
    __syncthreads();
    if (wv == 2)      STORE_ACC(gredA)
    __syncthreads();
    if (wv == 0) { ADD_ACC(gredA) STORE_ACC(gredA) }
    __syncthreads();

    // pointwise: thread -> (batch pb, units u0,u0+1)
    float hv[2];
#pragma unroll
    for (int d = 0; d < 2; ++d) {
      int u = u0 + d;
      float iv = gredA[pb][u]      + xq[d][0];
      float fv = gredA[pb][8 + u]  + xq[d][1];
      float gv = gredA[pb][16 + u] + xq[d][2];
      float ov = gredA[pb][24 + u] + xq[d][3];
      iv = 1.f / (1.f + __expf(-iv));
      fv = 1.f / (1.f + __expf(-fv));
      gv = tanhf(gv);
      ov = 1.f / (1.f + __expf(-ov));
      float cv = fv * (d ? cR1 : cR0) + iv * gv;
      if (d) cR1 = cv; else cR0 = cv;
      hv[d] = ov * tanhf(cv);
    }
    unsigned short h0b = bfbits(hv[0]), h1b = bfbits(hv[1]);
    unsigned short l0b = bfbits(hv[0] - bf2f(h0b));
    unsigned short l1b = bfbits(hv[1] - bf2f(h1b));
    unsigned hiW = (unsigned)h0b | ((unsigned)h1b << 16);
    unsigned loW = (unsigned)l0b | ((unsigned)l1b << 16);

    size_t wpar = (size_t)((s & 1) ^ 1) * 65536;
    size_t eo = ((size_t)((pb >> 4) * 32 + (wg >> 2)) * 64 + ((wg & 3) * 16 + (pb & 15))) * 8 + u0;
    *reinterpret_cast<unsigned*>(hfh + wpar + eo) = hiW;
    *reinterpret_cast<unsigned*>(hfl + wpar + eo) = loW;
    if (svh) {
      size_t so = (size_t)(s * 64 + pb) * HH + j0 + u0;
      *reinterpret_cast<unsigned*>(svh + so) = hiW;
      *reinterpret_cast<unsigned*>(svl + so) = loW;
    }
    if (outp) {
      float2 ov2 = make_float2(hv[0], hv[1]);
      *reinterpret_cast<float2*>(outp + (size_t)(s * 64 + pb) * HH + j0 + u0) = ov2;
    }

    // grid barrier (skip after last step)
    if (s + 1 < CT) {
      __syncthreads();   // all stores drained (compiler emits vmcnt(0) before s_barrier)
      if (tid == 0) {
        __hip_atomic_fetch_add(&flags[s], 1, __ATOMIC_RELEASE, __HIP_MEMORY_SCOPE_AGENT);
        while (__hip_atomic_load(&flags[s], __ATOMIC_ACQUIRE, __HIP_MEMORY_SCOPE_AGENT) < NWG)
          __builtin_amdgcn_s_sleep(2);
      }
      __syncthreads();
      __builtin_amdgcn_fence(__ATOMIC_ACQUIRE, "agent");  // invalidate stale h in caches
    }
  }

  cst[(size_t)pb * HH + j0 + u0]     = cR0;
  cst[(size_t)pb * HH + j0 + u0 + 1] = cR1;
}

extern "C" void kernel_launch(void* const* d_in, const int* in_sizes, int n_in,
                              void* d_out, int out_size, void* d_ws, size_t ws_size,
                              hipStream_t stream) {
  const float* x    = (const float*)d_in[0];
  const float* wih0 = (const float*)d_in[1];
  const float* whh0 = (const float*)d_in[2];
  const float* bih0 = (const float*)d_in[3];
  const float* bhh0 = (const float*)d_in[4];
  const float* wih1 = (const float*)d_in[5];
  const float* whh1 = (const float*)d_in[6];
  const float* bih1 = (const float*)d_in[7];
  const float* bhh1 = (const float*)d_in[8];
  float* out = (float*)d_out;

  int ct = 64;
  for (;;) {
    size_t fixed = (size_t)TT * BB * DD * 2 * 2
                 + (size_t)NG4 * DD * 2 * 2
                 + (size_t)NG4 * HH * 2 * 2
                 + (size_t)NG4 * HH * 2 * 2 * 2     // packed whh frag hi/lo x2 layers
                 + (size_t)4 * 2 * 65536 * 2        // hfrag ping-pong x2 layers
                 + (size_t)2 * BB * HH * 4          // c states
                 + ((size_t)1 << 18);
    size_t var = (size_t)2 * ct * BB * NG4 * 4 + (size_t)2 * ct * BB * HH * 2;
    if (fixed + var <= ws_size || ct == 8) break;
    ct >>= 1;
  }
  const int nch = TT / ct;

  char* ws = (char*)d_ws;
  size_t off = 0;
  auto alloc = [&](size_t bytes) -> char* {
    char* p = ws + off;
    off += (bytes + 255) & ~(size_t)255;
    return p;
  };
  bf16*  xh    = (bf16*)alloc((size_t)TT * BB * DD * 2);
  bf16*  xl    = (bf16*)alloc((size_t)TT * BB * DD * 2);
  bf16*  w0h   = (bf16*)alloc((size_t)NG4 * DD * 2);
  bf16*  w0l   = (bf16*)alloc((size_t)NG4 * DD * 2);
  bf16*  w1h   = (bf16*)alloc((size_t)NG4 * HH * 2);
  bf16*  w1l   = (bf16*)alloc((size_t)NG4 * HH * 2);
  bf16*  wpk0h = (bf16*)alloc((size_t)NG4 * HH * 2);
  bf16*  wpk0l = (bf16*)alloc((size_t)NG4 * HH * 2);
  bf16*  wpk1h = (bf16*)alloc((size_t)NG4 * HH * 2);
  bf16*  wpk1l = (bf16*)alloc((size_t)NG4 * HH * 2);
  bf16*  h1sh  = (bf16*)alloc((size_t)ct * BB * HH * 2);
  bf16*  h1sl  = (bf16*)alloc((size_t)ct * BB * HH * 2);
  float* xgT0  = (float*)alloc((size_t)ct * BB * NG4 * 4);
  float* xgT1  = (float*)alloc((size_t)ct * BB * NG4 * 4);
  bf16*  hf0h  = (bf16*)alloc((size_t)2 * 65536 * 2);
  bf16*  hf0l  = (bf16*)alloc((size_t)2 * 65536 * 2);
  bf16*  hf1h  = (bf16*)alloc((size_t)2 * 65536 * 2);
  bf16*  hf1l  = (bf16*)alloc((size_t)2 * 65536 * 2);
  float* c0    = (float*)alloc((size_t)BB * HH * 4);
  float* c1    = (float*)alloc((size_t)BB * HH * 4);
  int*   flags0 = (int*)alloc((size_t)ct * 4);
  int*   flags1 = (int*)alloc((size_t)ct * 4);

  cast_hilo<<<(TT * BB * DD / 4 + 255) / 256, 256, 0, stream>>>(x, xh, xl, TT * BB * DD / 4);
  cast_hilo<<<(NG4 * DD / 4 + 255) / 256, 256, 0, stream>>>(wih0, w0h, w0l, NG4 * DD / 4);
  cast_hilo<<<(NG4 * HH / 4 + 255) / 256, 256, 0, stream>>>(wih1, w1h, w1l, NG4 * HH / 4);
  pack_whh_frag<<<2048, 256, 0, stream>>>(whh0, wpk0h, wpk0l);
  pack_whh_frag<<<2048, 256, 0, stream>>>(whh1, wpk1h, wpk1l);

  hipMemsetAsync(hf0h, 0, (size_t)2 * 65536 * 2, stream);
  hipMemsetAsync(hf0l, 0, (size_t)2 * 65536 * 2, stream);
  hipMemsetAsync(hf1h, 0, (size_t)2 * 65536 * 2, stream);
  hipMemsetAsync(hf1l, 0, (size_t)2 * 65536 * 2, stream);
  hipMemsetAsync(c0, 0, (size_t)BB * HH * 4, stream);
  hipMemsetAsync(c1, 0, (size_t)BB * HH * 4, stream);

  const int gemmGrid = (ct * BB / BM) * (NG4 / BN);

  for (int ch = 0; ch < nch; ++ch) {
    gemm3<<<gemmGrid, 256, 0, stream>>>(xh + (size_t)ch * ct * BB * DD,
                                        xl + (size_t)ch * ct * BB * DD,
                                        w0h, w0l, bih0, bhh0, xgT0, ct * BB, NG4, DD);
    hipMemsetAsync(flags0, 0, (size_t)ct * 4, stream);
    lstm_scan<<<NWG, 256, 0, stream>>>(wpk0h, wpk0l, xgT0, hf0h, hf0l, c0, flags0, ct,
                                       h1sh, h1sl, (float*)nullptr);
    gemm3<<<gemmGrid, 256, 0, stream>>>(h1sh, h1sl, w1h, w1l, bih1, bhh1, xgT1,
                                        ct * BB, NG4, HH);
    hipMemsetAsync(flags1, 0, (size_t)ct * 4, stream);
    lstm_scan<<<NWG, 256, 0, stream>>>(wpk1h, wpk1l, xgT1, hf1h, hf1l, c1, flags1, ct,
                                       (bf16*)nullptr, (bf16*)nullptr,
                                       out + (size_t)ch * ct * BB * HH);
  }
}

// Round 4
// 20841.667 us; speedup vs baseline: 1.4040x; 1.4040x over previous
//
#include <hip/hip_runtime.h>
#include <hip/hip_bf16.h>

#define TT 512
#define BB 64
#define DD 1024
#define HH 1024
#define NG4 4096
#define NWG 128

typedef short bf16x8 __attribute__((ext_vector_type(8)));
typedef float f32x4 __attribute__((ext_vector_type(4)));
typedef __hip_bfloat16 bf16;

static __device__ __forceinline__ unsigned short bfbits(float f) {
  bf16 h = __float2bfloat16(f);
  return *reinterpret_cast<unsigned short*>(&h);
}
static __device__ __forceinline__ float bf2f(unsigned short u) {
  bf16 h = *reinterpret_cast<bf16*>(&u);
  return __bfloat162float(h);
}
// 16B load from the device-coherent point (bypasses non-coherent L1/L2), no fence
static __device__ __forceinline__ bf16x8 ld_agent16(const bf16* p) {
  union { unsigned long long q[2]; bf16x8 v; } u;
  u.q[0] = __hip_atomic_load((const unsigned long long*)p,     __ATOMIC_RELAXED, __HIP_MEMORY_SCOPE_AGENT);
  u.q[1] = __hip_atomic_load((const unsigned long long*)p + 1, __ATOMIC_RELAXED, __HIP_MEMORY_SCOPE_AGENT);
  return u.v;
}
static __device__ __forceinline__ void st_agent4(void* p, unsigned v) {
  __hip_atomic_store((unsigned*)p, v, __ATOMIC_RELAXED, __HIP_MEMORY_SCOPE_AGENT);
}

// ---------------- cast: fp32 -> bf16 hi + bf16 lo(residual) ----------------
__global__ __launch_bounds__(256) void cast_hilo(const float* __restrict__ in,
                                                 bf16* __restrict__ hi,
                                                 bf16* __restrict__ lo,
                                                 int n4) {
  int i = blockIdx.x * 256 + threadIdx.x;
  if (i >= n4) return;
  float4 v = reinterpret_cast<const float4*>(in)[i];
  float f[4] = {v.x, v.y, v.z, v.w};
  int base = i * 4;
#pragma unroll
  for (int j = 0; j < 4; ++j) {
    bf16 h = __float2bfloat16(f[j]);
    hi[base + j] = h;
    lo[base + j] = __float2bfloat16(f[j] - __bfloat162float(h));
  }
}

// ---------------- pack w_hh into per-WG fragment-major hi/lo ----------------
__global__ __launch_bounds__(256) void pack_whh_frag(const float* __restrict__ w,
                                                     bf16* __restrict__ ph,
                                                     bf16* __restrict__ pl) {
  int gid = blockIdx.x * 256 + threadIdx.x;   // 128*4096 groups
  int wg  = gid >> 12;
  int rem = gid & 4095;
  int kc = rem >> 7, n = (rem >> 6) & 1, l = rem & 63;
  int p = n * 16 + (l & 15);
  int q = p >> 3, u = p & 7;
  int k = kc * 32 + (l >> 4) * 8;
  size_t src = (size_t)(q * 1024 + wg * 8 + u) * HH + k;
  float4 v0 = *reinterpret_cast<const float4*>(w + src);
  float4 v1 = *reinterpret_cast<const float4*>(w + src + 4);
  float f[8] = {v0.x, v0.y, v0.z, v0.w, v1.x, v1.y, v1.z, v1.w};
  short ho[8], lo[8];
#pragma unroll
  for (int j = 0; j < 8; ++j) {
    unsigned short hb = bfbits(f[j]);
    ho[j] = (short)hb;
    lo[j] = (short)bfbits(f[j] - bf2f(hb));
  }
  *reinterpret_cast<bf16x8*>(ph + (size_t)gid * 8) = *reinterpret_cast<bf16x8*>(ho);
  *reinterpret_cast<bf16x8*>(pl + (size_t)gid * 8) = *reinterpret_cast<bf16x8*>(lo);
}

// ---------------- 3-term split-bf16 MFMA GEMM, transposed epilogue ----------
#define BM 128
#define BN 128
#define BKK 64

__global__ __launch_bounds__(256) void gemm3(
    const bf16* __restrict__ Ah, const bf16* __restrict__ Al,
    const bf16* __restrict__ Bh, const bf16* __restrict__ Bl,
    const float* __restrict__ bias1, const float* __restrict__ bias2,
    float* __restrict__ C, int M, int N, int K)
{
  __shared__ bf16 sAh[BM][BKK], sAl[BM][BKK], sBh[BN][BKK], sBl[BN][BKK];
  const int tid  = threadIdx.x;
  const int lane = tid & 63;
  const int wv   = tid >> 6;
  const int wr   = wv >> 1, wc = wv & 1;
  const int nbx  = N / BN;
  const int bx   = blockIdx.x % nbx, by = blockIdx.x / nbx;
  const int l15  = lane & 15, l4 = lane >> 4;

  f32x4 acc[4][4] = {};

  for (int k0 = 0; k0 < K; k0 += BKK) {
    __syncthreads();
#pragma unroll
    for (int i = 0; i < 4; ++i) {
      int f  = i * 256 + tid;
      int r  = f >> 3;
      int kk = (f & 7) << 3;
      size_t ga = (size_t)(by * BM + r) * K + k0 + kk;
      size_t gb = (size_t)(bx * BN + r) * K + k0 + kk;
      *reinterpret_cast<bf16x8*>(&sAh[r][kk]) = *reinterpret_cast<const bf16x8*>(Ah + ga);
      *reinterpret_cast<bf16x8*>(&sAl[r][kk]) = *reinterpret_cast<const bf16x8*>(Al + ga);
      *reinterpret_cast<bf16x8*>(&sBh[r][kk]) = *reinterpret_cast<const bf16x8*>(Bh + gb);
      *reinterpret_cast<bf16x8*>(&sBl[r][kk]) = *reinterpret_cast<const bf16x8*>(Bl + gb);
    }
    __syncthreads();
#pragma unroll
    for (int kk = 0; kk < BKK; kk += 32) {
      const int kf = kk + (l4 << 3);
      bf16x8 a_h[4], a_l[4], b_h[4], b_l[4];
#pragma unroll
      for (int m = 0; m < 4; ++m) {
        a_h[m] = *reinterpret_cast<const bf16x8*>(&sAh[wr * 64 + m * 16 + l15][kf]);
        a_l[m] = *reinterpret_cast<const bf16x8*>(&sAl[wr * 64 + m * 16 + l15][kf]);
      }
#pragma unroll
      for (int n = 0; n < 4; ++n) {
        b_h[n] = *reinterpret_cast<const bf16x8*>(&sBh[wc * 64 + n * 16 + l15][kf]);
        b_l[n] = *reinterpret_cast<const bf16x8*>(&sBl[wc * 64 + n * 16 + l15][kf]);
      }
#pragma unroll
      for (int m = 0; m < 4; ++m)
#pragma unroll
        for (int n = 0; n < 4; ++n) {
          acc[m][n] = __builtin_amdgcn_mfma_f32_16x16x32_bf16(a_h[m], b_h[n], acc[m][n], 0, 0, 0);
          acc[m][n] = __builtin_amdgcn_mfma_f32_16x16x32_bf16(a_l[m], b_h[n], acc[m][n], 0, 0, 0);
          acc[m][n] = __builtin_amdgcn_mfma_f32_16x16x32_bf16(a_h[m], b_l[n], acc[m][n], 0, 0, 0);
        }
    }
  }
#pragma unroll
  for (int n = 0; n < 4; ++n) {
    int col = bx * BN + wc * 64 + n * 16 + l15;
    float bv = bias1[col] + bias2[col];
#pragma unroll
    for (int m = 0; m < 4; ++m) {
      int row0 = by * BM + wr * 64 + m * 16 + l4 * 4;
      int t = row0 >> 6, b0 = row0 & 63;
      float4 v;
      v.x = acc[m][n][0] + bv;
      v.y = acc[m][n][1] + bv;
      v.z = acc[m][n][2] + bv;
      v.w = acc[m][n][3] + bv;
      *reinterpret_cast<float4*>(C + (size_t)t * (NG4 * 64) + (size_t)col * 64 + b0) = v;
    }
  }
}

// ---------------- persistent chunk scan: CT timesteps, flag-array barrier --
__global__ __launch_bounds__(256, 1) void lstm_scan(
    const bf16* __restrict__ wpkh, const bf16* __restrict__ wpkl, // [128][32768]
    const float* __restrict__ xgT,   // [CT][4096][64], biases included
    bf16* __restrict__ hfh, bf16* __restrict__ hfl,  // [2][65536]
    float* __restrict__ cst,         // [64][1024]
    int* __restrict__ flags,         // [NWG], zeroed
    int CT,
    bf16* __restrict__ svh, bf16* __restrict__ svl,  // [CT*64][1024] or null
    float* __restrict__ outp)        // [CT*64][1024] or null
{
  __shared__ bf16  sW[65536];        // hi at [0,32768), lo at [32768,65536)
  __shared__ float gredA[64][33];
  __shared__ float gredB[64][33];

  const int tid  = threadIdx.x;
  const int lane = tid & 63;
  const int wv   = tid >> 6;
  const int wg   = blockIdx.x;
  const int l15  = lane & 15, l4 = lane >> 4;
  const int j0   = wg * 8;

  // load w into LDS once
  {
    const bf16x8* srcH = reinterpret_cast<const bf16x8*>(wpkh + (size_t)wg * 32768);
    const bf16x8* srcL = reinterpret_cast<const bf16x8*>(wpkl + (size_t)wg * 32768);
    bf16x8* dstH = reinterpret_cast<bf16x8*>(sW);
    bf16x8* dstL = reinterpret_cast<bf16x8*>(sW + 32768);
    for (int i = tid; i < 4096; i += 256) { dstH[i] = srcH[i]; dstL[i] = srcL[i]; }
  }
  const int pb = tid & 63;        // pointwise: batch
  const int u0 = (tid >> 6) * 2;  // pointwise: unit pair
  float cR0 = cst[(size_t)pb * HH + j0 + u0];
  float cR1 = cst[(size_t)pb * HH + j0 + u0 + 1];
  __syncthreads();

  for (int s = 0; s < CT; ++s) {
    const bf16* hh = hfh + (size_t)(s & 1) * 65536;
    const bf16* hl = hfl + (size_t)(s & 1) * 65536;

    // prefetch xg for this thread's pointwise (normal cached loads; produced
    // by a prior dispatch so dispatch-boundary visibility applies)
    const float* xgs = xgT + (size_t)s * (NG4 * 64);
    float xq[2][4];
#pragma unroll
    for (int d = 0; d < 2; ++d) {
      int u = j0 + u0 + d;
#pragma unroll
      for (int q = 0; q < 4; ++q)
        xq[d][q] = xgs[(size_t)(q * 1024 + u) * 64 + pb];
    }

    f32x4 acc[4][2] = {};
#pragma unroll
    for (int kk = 0; kk < 8; ++kk) {
      const int kc = wv * 8 + kk;
      bf16x8 bh[2], bl[2];
#pragma unroll
      for (int n = 0; n < 2; ++n) {
        const int wi = ((kc * 2 + n) * 64 + lane) * 8;
        bh[n] = *reinterpret_cast<const bf16x8*>(sW + wi);
        bl[n] = *reinterpret_cast<const bf16x8*>(sW + 32768 + wi);
      }
#pragma unroll
      for (int m = 0; m < 4; ++m) {
        const size_t ai = ((size_t)(m * 32 + kc) * 64 + lane) * 8;
        bf16x8 ah = ld_agent16(hh + ai);
        bf16x8 al = ld_agent16(hl + ai);
#pragma unroll
        for (int n = 0; n < 2; ++n) {
          acc[m][n] = __builtin_amdgcn_mfma_f32_16x16x32_bf16(ah, bh[n], acc[m][n], 0, 0, 0);
          acc[m][n] = __builtin_amdgcn_mfma_f32_16x16x32_bf16(al, bh[n], acc[m][n], 0, 0, 0);
          acc[m][n] = __builtin_amdgcn_mfma_f32_16x16x32_bf16(ah, bl[n], acc[m][n], 0, 0, 0);
        }
      }
    }

    // cross-wave K reduction (tree via LDS)
#define STORE_ACC(G)                                            \
    {_Pragma("unroll") for (int m = 0; m < 4; ++m)              \
     _Pragma("unroll") for (int n = 0; n < 2; ++n)              \
     _Pragma("unroll") for (int r = 0; r < 4; ++r)              \
       G[m * 16 + l4 * 4 + r][n * 16 + l15] = acc[m][n][r];}
#define ADD_ACC(G)                                              \
    {_Pragma("unroll") for (int m = 0; m < 4; ++m)              \
     _Pragma("unroll") for (int n = 0; n < 2; ++n)              \
     _Pragma("unroll") for (int r = 0; r < 4; ++r)              \
       acc[m][n][r] += G[m * 16 + l4 * 4 + r][n * 16 + l15];}

    if (wv == 1)      STORE_ACC(gredA)
    else if (wv == 3) STORE_ACC(gredB)
    __syncthreads();
    if (wv == 0)      ADD_ACC(gredA)
    else if (wv == 2) ADD_ACC(gredB)
    __syncthreads();
    if (wv == 2)      STORE_ACC(gredA)
    __syncthreads();
    if (wv == 0) { ADD_ACC(gredA) STORE_ACC(gredA) }
    __syncthreads();

    // pointwise: thread -> (batch pb, units u0,u0+1)
    float hv[2];
#pragma unroll
    for (int d = 0; d < 2; ++d) {
      int u = u0 + d;
      float iv = gredA[pb][u]      + xq[d][0];
      float fv = gredA[pb][8 + u]  + xq[d][1];
      float gv = gredA[pb][16 + u] + xq[d][2];
      float ov = gredA[pb][24 + u] + xq[d][3];
      iv = 1.f / (1.f + __expf(-iv));
      fv = 1.f / (1.f + __expf(-fv));
      gv = tanhf(gv);
      ov = 1.f / (1.f + __expf(-ov));
      float cv = fv * (d ? cR1 : cR0) + iv * gv;
      if (d) cR1 = cv; else cR0 = cv;
      hv[d] = ov * tanhf(cv);
    }
    unsigned short h0b = bfbits(hv[0]), h1b = bfbits(hv[1]);
    unsigned short l0b = bfbits(hv[0] - bf2f(h0b));
    unsigned short l1b = bfbits(hv[1] - bf2f(h1b));
    unsigned hiW = (unsigned)h0b | ((unsigned)h1b << 16);
    unsigned loW = (unsigned)l0b | ((unsigned)l1b << 16);

    size_t wpar = (size_t)((s & 1) ^ 1) * 65536;
    size_t eo = ((size_t)((pb >> 4) * 32 + (wg >> 2)) * 64 + ((wg & 3) * 16 + (pb & 15))) * 8 + u0;
    st_agent4(hfh + wpar + eo, hiW);   // coherent-point stores: next step's
    st_agent4(hfl + wpar + eo, loW);   // agent loads see them, no fence needed
    if (svh) {
      size_t so = (size_t)(s * 64 + pb) * HH + j0 + u0;
      *reinterpret_cast<unsigned*>(svh + so) = hiW;
      *reinterpret_cast<unsigned*>(svl + so) = loW;
    }
    if (outp) {
      float2 ov2 = make_float2(hv[0], hv[1]);
      *reinterpret_cast<float2*>(outp + (size_t)(s * 64 + pb) * HH + j0 + u0) = ov2;
    }

    // grid barrier (skip after last step): flag-array, no RMW, no fences
    if (s + 1 < CT) {
      __syncthreads();   // drains vmcnt(0): all h stores complete before signal
      if (tid == 0)
        __hip_atomic_store(&flags[wg], s + 1, __ATOMIC_RELAXED, __HIP_MEMORY_SCOPE_AGENT);
      if (tid < NWG) {
        while (__hip_atomic_load(&flags[tid], __ATOMIC_RELAXED, __HIP_MEMORY_SCOPE_AGENT) <= s)
          __builtin_amdgcn_s_sleep(1);
      }
      __syncthreads();
    }
  }

  cst[(size_t)pb * HH + j0 + u0]     = cR0;
  cst[(size_t)pb * HH + j0 + u0 + 1] = cR1;
}

extern "C" void kernel_launch(void* const* d_in, const int* in_sizes, int n_in,
                              void* d_out, int out_size, void* d_ws, size_t ws_size,
                              hipStream_t stream) {
  const float* x    = (const float*)d_in[0];
  const float* wih0 = (const float*)d_in[1];
  const float* whh0 = (const float*)d_in[2];
  const float* bih0 = (const float*)d_in[3];
  const float* bhh0 = (const float*)d_in[4];
  const float* wih1 = (const float*)d_in[5];
  const float* whh1 = (const float*)d_in[6];
  const float* bih1 = (const float*)d_in[7];
  const float* bhh1 = (const float*)d_in[8];
  float* out = (float*)d_out;

  int ct = 64;
  for (;;) {
    size_t fixed = (size_t)TT * BB * DD * 2 * 2
                 + (size_t)NG4 * DD * 2 * 2
                 + (size_t)NG4 * HH * 2 * 2
                 + (size_t)NG4 * HH * 2 * 2 * 2     // packed whh frag hi/lo x2 layers
                 + (size_t)4 * 2 * 65536 * 2        // hfrag ping-pong x2 layers
                 + (size_t)2 * BB * HH * 4          // c states
                 + ((size_t)1 << 18);
    size_t var = (size_t)2 * ct * BB * NG4 * 4 + (size_t)2 * ct * BB * HH * 2;
    if (fixed + var <= ws_size || ct == 8) break;
    ct >>= 1;
  }
  const int nch = TT / ct;

  char* ws = (char*)d_ws;
  size_t off = 0;
  auto alloc = [&](size_t bytes) -> char* {
    char* p = ws + off;
    off += (bytes + 255) & ~(size_t)255;
    return p;
  };
  bf16*  xh    = (bf16*)alloc((size_t)TT * BB * DD * 2);
  bf16*  xl    = (bf16*)alloc((size_t)TT * BB * DD * 2);
  bf16*  w0h   = (bf16*)alloc((size_t)NG4 * DD * 2);
  bf16*  w0l   = (bf16*)alloc((size_t)NG4 * DD * 2);
  bf16*  w1h   = (bf16*)alloc((size_t)NG4 * HH * 2);
  bf16*  w1l   = (bf16*)alloc((size_t)NG4 * HH * 2);
  bf16*  wpk0h = (bf16*)alloc((size_t)NG4 * HH * 2);
  bf16*  wpk0l = (bf16*)alloc((size_t)NG4 * HH * 2);
  bf16*  wpk1h = (bf16*)alloc((size_t)NG4 * HH * 2);
  bf16*  wpk1l = (bf16*)alloc((size_t)NG4 * HH * 2);
  bf16*  h1sh  = (bf16*)alloc((size_t)ct * BB * HH * 2);
  bf16*  h1sl  = (bf16*)alloc((size_t)ct * BB * HH * 2);
  float* xgT0  = (float*)alloc((size_t)ct * BB * NG4 * 4);
  float* xgT1  = (float*)alloc((size_t)ct * BB * NG4 * 4);
  bf16*  hf0h  = (bf16*)alloc((size_t)2 * 65536 * 2);
  bf16*  hf0l  = (bf16*)alloc((size_t)2 * 65536 * 2);
  bf16*  hf1h  = (bf16*)alloc((size_t)2 * 65536 * 2);
  bf16*  hf1l  = (bf16*)alloc((size_t)2 * 65536 * 2);
  float* c0    = (float*)alloc((size_t)BB * HH * 4);
  float* c1    = (float*)alloc((size_t)BB * HH * 4);
  int*   flags0 = (int*)alloc((size_t)NWG * 4);
  int*   flags1 = (int*)alloc((size_t)NWG * 4);

  cast_hilo<<<(TT * BB * DD / 4 + 255) / 256, 256, 0, stream>>>(x, xh, xl, TT * BB * DD / 4);
  cast_hilo<<<(NG4 * DD / 4 + 255) / 256, 256, 0, stream>>>(wih0, w0h, w0l, NG4 * DD / 4);
  cast_hilo<<<(NG4 * HH / 4 + 255) / 256, 256, 0, stream>>>(wih1, w1h, w1l, NG4 * HH / 4);
  pack_whh_frag<<<2048, 256, 0, stream>>>(whh0, wpk0h, wpk0l);
  pack_whh_frag<<<2048, 256, 0, stream>>>(whh1, wpk1h, wpk1l);

  hipMemsetAsync(hf0h, 0, (size_t)2 * 65536 * 2, stream);
  hipMemsetAsync(hf0l, 0, (size_t)2 * 65536 * 2, stream);
  hipMemsetAsync(hf1h, 0, (size_t)2 * 65536 * 2, stream);
  hipMemsetAsync(hf1l, 0, (size_t)2 * 65536 * 2, stream);
  hipMemsetAsync(c0, 0, (size_t)BB * HH * 4, stream);
  hipMemsetAsync(c1, 0, (size_t)BB * HH * 4, stream);

  const int gemmGrid = (ct * BB / BM) * (NG4 / BN);

  for (int ch = 0; ch < nch; ++ch) {
    gemm3<<<gemmGrid, 256, 0, stream>>>(xh + (size_t)ch * ct * BB * DD,
                                        xl + (size_t)ch * ct * BB * DD,
                                        w0h, w0l, bih0, bhh0, xgT0, ct * BB, NG4, DD);
    hipMemsetAsync(flags0, 0, (size_t)NWG * 4, stream);
    lstm_scan<<<NWG, 256, 0, stream>>>(wpk0h, wpk0l, xgT0, hf0h, hf0l, c0, flags0, ct,
                                       h1sh, h1sl, (float*)nullptr);
    gemm3<<<gemmGrid, 256, 0, stream>>>(h1sh, h1sl, w1h, w1l, bih1, bhh1, xgT1,
                                        ct * BB, NG4, HH);
    hipMemsetAsync(flags1, 0, (size_t)NWG * 4, stream);
    lstm_scan<<<NWG, 256, 0, stream>>>(wpk1h, wpk1l, xgT1, hf1h, hf1l, c1, flags1, ct,
                                       (bf16*)nullptr, (bf16*)nullptr,
                                       out + (size_t)ch * ct * BB * HH);
  }
}